// Round 1
// baseline (932.859 us; speedup 1.0000x reference)
//
#include <hip/hip_runtime.h>
#include <hip/hip_bf16.h>

// ---------------------------------------------------------------------------
// PatchGAT: 3x (GATConv -> relu -> [dense -> relu]) -> head-mean -> graph-max
// fp32 baseline. N=20000, E=320000, F_IN=HID=OUT=128, H=4, H*D=512.
// ---------------------------------------------------------------------------

#define BM 64
#define BN 64
#define BK 16

// ---------------- generic fp32 tiled GEMM: C = A[M,K] @ B[K,N] (+bias, relu)
template <bool BIAS_RELU>
__global__ __launch_bounds__(256) void gemm_kernel(
    const float* __restrict__ A, const float* __restrict__ B,
    const float* __restrict__ bias, float* __restrict__ C,
    int M, int N, int K) {
  __shared__ float As[BK][BM + 4];
  __shared__ float Bs[BK][BN + 4];
  int tid = threadIdx.x;
  int tx = tid & 15, ty = tid >> 4;
  int rowBase = blockIdx.y * BM;
  int colBase = blockIdx.x * BN;
  int arow = tid >> 2;           // 0..63
  int akq = (tid & 3) * 4;       // 0,4,8,12
  int brow = tid >> 4;           // 0..15
  int bcol = (tid & 15) * 4;     // 0..60

  float acc[4][4] = {};

  for (int k0 = 0; k0 < K; k0 += BK) {
    float4 av = make_float4(0.f, 0.f, 0.f, 0.f);
    int ar = rowBase + arow;
    if (ar < M) av = *(const float4*)(A + (size_t)ar * K + k0 + akq);
    As[akq + 0][arow] = av.x;
    As[akq + 1][arow] = av.y;
    As[akq + 2][arow] = av.z;
    As[akq + 3][arow] = av.w;

    float4 bv = *(const float4*)(B + (size_t)(k0 + brow) * N + colBase + bcol);
    *(float4*)&Bs[brow][bcol] = bv;
    __syncthreads();

#pragma unroll
    for (int kk = 0; kk < BK; kk++) {
      float4 a = *(const float4*)&As[kk][ty * 4];
      float4 b = *(const float4*)&Bs[kk][tx * 4];
      acc[0][0] += a.x * b.x; acc[0][1] += a.x * b.y; acc[0][2] += a.x * b.z; acc[0][3] += a.x * b.w;
      acc[1][0] += a.y * b.x; acc[1][1] += a.y * b.y; acc[1][2] += a.y * b.z; acc[1][3] += a.y * b.w;
      acc[2][0] += a.z * b.x; acc[2][1] += a.z * b.y; acc[2][2] += a.z * b.z; acc[2][3] += a.z * b.w;
      acc[3][0] += a.w * b.x; acc[3][1] += a.w * b.y; acc[3][2] += a.w * b.z; acc[3][3] += a.w * b.w;
    }
    __syncthreads();
  }

  float4 bb = make_float4(0.f, 0.f, 0.f, 0.f);
  if (BIAS_RELU) bb = *(const float4*)(bias + colBase + tx * 4);
#pragma unroll
  for (int i = 0; i < 4; i++) {
    int r = rowBase + ty * 4 + i;
    if (r >= M) continue;
    float4 o = make_float4(acc[i][0], acc[i][1], acc[i][2], acc[i][3]);
    if (BIAS_RELU) {
      o.x = fmaxf(o.x + bb.x, 0.f);
      o.y = fmaxf(o.y + bb.y, 0.f);
      o.z = fmaxf(o.z + bb.z, 0.f);
      o.w = fmaxf(o.w + bb.w, 0.f);
    }
    *(float4*)(C + (size_t)r * N + colBase + tx * 4) = o;
  }
}

// ---------------- el/er: per (node, head) dot of feat with attn vectors
__global__ __launch_bounds__(256) void el_er_kernel(
    const float* __restrict__ feat, const float* __restrict__ al,
    const float* __restrict__ ar, float* __restrict__ el,
    float* __restrict__ er, int N) {
  int n = blockIdx.x;
  int h = threadIdx.x >> 6;
  int l = threadIdx.x & 63;
  const float2 fv = *(const float2*)(feat + (size_t)n * 512 + h * 128 + l * 2);
  const float2 av = *(const float2*)(al + h * 128 + l * 2);
  const float2 bv = *(const float2*)(ar + h * 128 + l * 2);
  float sl = fv.x * av.x + fv.y * av.y;
  float sr = fv.x * bv.x + fv.y * bv.y;
  for (int off = 32; off; off >>= 1) {
    sl += __shfl_down(sl, off);
    sr += __shfl_down(sr, off);
  }
  if (l == 0) {
    el[n * 4 + h] = sl;
    er[n * 4 + h] = sr;
  }
}

// ---------------- CSR build
__global__ __launch_bounds__(256) void count_kernel(const int* __restrict__ dst,
                                                    int* __restrict__ counts, int E) {
  int i = blockIdx.x * blockDim.x + threadIdx.x;
  if (i < E) atomicAdd(&counts[dst[i]], 1);
}

__global__ __launch_bounds__(1024) void scan_kernel(const int* __restrict__ counts,
                                                    int* __restrict__ row_ptr,
                                                    int* __restrict__ cursor, int N) {
  __shared__ int sums[1024];
  int t = threadIdx.x;
  int chunk = (N + 1023) / 1024;
  int begin = t * chunk;
  int end = begin + chunk;
  if (end > N) end = N;
  int s = 0;
  for (int i = begin; i < end; i++) s += counts[i];
  sums[t] = s;
  __syncthreads();
  for (int off = 1; off < 1024; off <<= 1) {
    int v = (t >= off) ? sums[t - off] : 0;
    __syncthreads();
    sums[t] += v;
    __syncthreads();
  }
  int run = (t == 0) ? 0 : sums[t - 1];
  for (int i = begin; i < end; i++) {
    row_ptr[i] = run;
    cursor[i] = run;
    run += counts[i];
  }
  if (t == 1023) row_ptr[N] = sums[1023];
}

__global__ __launch_bounds__(256) void scatter_kernel(
    const int* __restrict__ src, const int* __restrict__ dst,
    int* __restrict__ cursor, int* __restrict__ edge_src, int E) {
  int i = blockIdx.x * blockDim.x + threadIdx.x;
  if (i < E) {
    int d = dst[i];
    int pos = atomicAdd(&cursor[d], 1);
    edge_src[pos] = src[i];
  }
}

// ---------------- GAT aggregation: per node n (block), per head h (wave)
// two-pass edge softmax + weighted gather; out = relu(agg + res + bias)
__global__ __launch_bounds__(256) void gat_agg_kernel(
    const float* __restrict__ feat, const float* __restrict__ res,
    const float* __restrict__ el, const float* __restrict__ er,
    const float* __restrict__ bias, const int* __restrict__ row_ptr,
    const int* __restrict__ edge_src, float* __restrict__ out, int N) {
  int n = blockIdx.x;
  int h = threadIdx.x >> 6;
  int l = threadIdx.x & 63;
  int start = row_ptr[n];
  int deg = row_ptr[n + 1] - start;
  float er_nh = er[n * 4 + h];

  // pass 1: max over incoming-edge scores
  float m = -3.402823466e38f;
  for (int i = l; i < deg; i += 64) {
    int s = edge_src[start + i];
    float e = el[s * 4 + h] + er_nh;
    e = (e > 0.f) ? e : 0.2f * e;
    m = fmaxf(m, e);
  }
  for (int off = 32; off; off >>= 1) m = fmaxf(m, __shfl_xor(m, off));

  // pass 2: sum + weighted accumulate (all lanes walk all edges; lane = 2 dims)
  int d0 = l * 2;
  float acc0 = 0.f, acc1 = 0.f, ssum = 0.f;
  for (int i = 0; i < deg; i++) {
    int s = edge_src[start + i];
    float e = el[s * 4 + h] + er_nh;
    e = (e > 0.f) ? e : 0.2f * e;
    float w = __expf(e - m);
    ssum += w;
    const float2 fv = *(const float2*)(feat + (size_t)s * 512 + h * 128 + d0);
    acc0 += w * fv.x;
    acc1 += w * fv.y;
  }
  float inv = (deg > 0) ? 1.f / ssum : 0.f;
  size_t oidx = (size_t)n * 512 + h * 128 + d0;
  float2 r = *(const float2*)(res + oidx);
  float2 bv = *(const float2*)(bias + h * 128 + d0);
  float o0 = fmaxf(acc0 * inv + r.x + bv.x, 0.f);
  float o1 = fmaxf(acc1 * inv + r.y + bv.y, 0.f);
  *(float2*)(out + oidx) = make_float2(o0, o1);
}

// ---------------- final: head-mean -> relu -> max over nodes
__global__ __launch_bounds__(128) void pool_kernel(const float* __restrict__ g,
                                                   float* __restrict__ out, int N) {
  int d = threadIdx.x;  // 0..127
  float mx = 0.f;
  for (int n = blockIdx.x; n < N; n += gridDim.x) {
    const float* p = g + (size_t)n * 512 + d;
    float v = 0.25f * (p[0] + p[128] + p[256] + p[384]);
    mx = fmaxf(mx, v);
  }
  atomicMax((int*)out + d, __float_as_int(mx));  // values are >= 0
}

// ---------------------------------------------------------------------------
extern "C" void kernel_launch(void* const* d_in, const int* in_sizes, int n_in,
                              void* d_out, int out_size, void* d_ws, size_t ws_size,
                              hipStream_t stream) {
  const float* n_feat = (const float*)d_in[0];
  const int* src = (const int*)d_in[1];
  const int* dst = (const int*)d_in[2];
  const float* W0 = (const float*)d_in[3];
  const float* al0 = (const float*)d_in[4];
  const float* ar0 = (const float*)d_in[5];
  const float* b0 = (const float*)d_in[6];
  const float* rW0 = (const float*)d_in[7];
  const float* DW0 = (const float*)d_in[8];
  const float* Db0 = (const float*)d_in[9];
  const float* W1 = (const float*)d_in[10];
  const float* al1 = (const float*)d_in[11];
  const float* ar1 = (const float*)d_in[12];
  const float* b1 = (const float*)d_in[13];
  const float* rW1 = (const float*)d_in[14];
  const float* DW1 = (const float*)d_in[15];
  const float* Db1 = (const float*)d_in[16];
  const float* W2 = (const float*)d_in[17];
  const float* al2 = (const float*)d_in[18];
  const float* ar2 = (const float*)d_in[19];
  const float* b2 = (const float*)d_in[20];
  const float* rW2 = (const float*)d_in[21];

  const int N = in_sizes[0] / 128;
  const int E = in_sizes[1];

  // workspace carve-up (floats)
  float* bufA = (float*)d_ws;                       // feat    [N,512]
  float* bufB = bufA + (size_t)N * 512;             // res     [N,512]
  float* bufC = bufB + (size_t)N * 512;             // gat out [N,512]
  float* bufD = bufC + (size_t)N * 512;             // dense   [N,128]
  float* el = bufD + (size_t)N * 128;               // [N,4]
  float* er = el + (size_t)N * 4;                   // [N,4]
  int* counts = (int*)(er + (size_t)N * 4);         // [N]
  int* row_ptr = counts + N;                        // [N+1]
  int* cursor = row_ptr + (N + 1);                  // [N]
  int* edge_src = cursor + N;                       // [E]

  // ---- build CSR by dst (reused by all 3 layers)
  hipMemsetAsync(counts, 0, (size_t)N * sizeof(int), stream);
  count_kernel<<<(E + 255) / 256, 256, 0, stream>>>(dst, counts, E);
  scan_kernel<<<1, 1024, 0, stream>>>(counts, row_ptr, cursor, N);
  scatter_kernel<<<(E + 255) / 256, 256, 0, stream>>>(src, dst, cursor, edge_src, E);

  dim3 g512((512 + BN - 1) / BN, (N + BM - 1) / BM);
  dim3 g128((128 + BN - 1) / BN, (N + BM - 1) / BM);

  // ---- layer 0 (F_IN=128 -> H*D=512)
  gemm_kernel<false><<<g512, 256, 0, stream>>>(n_feat, W0, nullptr, bufA, N, 512, 128);
  gemm_kernel<false><<<g512, 256, 0, stream>>>(n_feat, rW0, nullptr, bufB, N, 512, 128);
  el_er_kernel<<<N, 256, 0, stream>>>(bufA, al0, ar0, el, er, N);
  gat_agg_kernel<<<N, 256, 0, stream>>>(bufA, bufB, el, er, b0, row_ptr, edge_src, bufC, N);
  gemm_kernel<true><<<g128, 256, 0, stream>>>(bufC, DW0, Db0, bufD, N, 128, 512);

  // ---- layer 1
  gemm_kernel<false><<<g512, 256, 0, stream>>>(bufD, W1, nullptr, bufA, N, 512, 128);
  gemm_kernel<false><<<g512, 256, 0, stream>>>(bufD, rW1, nullptr, bufB, N, 512, 128);
  el_er_kernel<<<N, 256, 0, stream>>>(bufA, al1, ar1, el, er, N);
  gat_agg_kernel<<<N, 256, 0, stream>>>(bufA, bufB, el, er, b1, row_ptr, edge_src, bufC, N);
  gemm_kernel<true><<<g128, 256, 0, stream>>>(bufC, DW1, Db1, bufD, N, 128, 512);

  // ---- layer 2 + pooling
  gemm_kernel<false><<<g512, 256, 0, stream>>>(bufD, W2, nullptr, bufA, N, 512, 128);
  gemm_kernel<false><<<g512, 256, 0, stream>>>(bufD, rW2, nullptr, bufB, N, 512, 128);
  el_er_kernel<<<N, 256, 0, stream>>>(bufA, al2, ar2, el, er, N);
  gat_agg_kernel<<<N, 256, 0, stream>>>(bufA, bufB, el, er, b2, row_ptr, edge_src, bufC, N);

  hipMemsetAsync(d_out, 0, 128 * sizeof(float), stream);
  pool_kernel<<<256, 128, 0, stream>>>(bufC, (float*)d_out, N);
}

// Round 2
// 613.641 us; speedup vs baseline: 1.5202x; 1.5202x over previous
//
#include <hip/hip_runtime.h>
#include <hip/hip_bf16.h>

// ---------------------------------------------------------------------------
// PatchGAT on MI355X. Round 2: bf16 MFMA GEMMs + bf16 activations.
// N=20000, E=320000, F_IN=HID=OUT=128, H=4, H*D=512.
// ---------------------------------------------------------------------------

typedef __attribute__((ext_vector_type(8))) short bf16x8;
typedef __attribute__((ext_vector_type(4))) float f32x4;
typedef __hip_bfloat16 bf16_t;

__device__ __forceinline__ float bf2f(unsigned short u) {
  union { float f; unsigned int i; } c;
  c.i = ((unsigned int)u) << 16;
  return c.f;
}

// ---------------- weight prep: fp32 [K,N] -> bf16 [N,K] (transpose+convert)
// mats 0..5: K=128,N=512 (W0,rW0,W1,rW1,W2,rW2); mats 6..7: K=512,N=128 (DW0,DW1)
__global__ __launch_bounds__(256) void prep_weights(
    const float* __restrict__ m0, const float* __restrict__ m1,
    const float* __restrict__ m2, const float* __restrict__ m3,
    const float* __restrict__ m4, const float* __restrict__ m5,
    const float* __restrict__ m6, const float* __restrict__ m7,
    bf16_t* __restrict__ out) {
  int idx = blockIdx.x * 256 + threadIdx.x;   // 0 .. 8*65536-1
  int mat = idx >> 16;
  int off = idx & 65535;
  const float* srcs[8] = {m0, m1, m2, m3, m4, m5, m6, m7};
  const float* s = srcs[mat];
  float v;
  if (mat < 6) {            // src [128,512]; out [n*128+k] = src[k*512+n]
    int n = off >> 7, k = off & 127;
    v = s[k * 512 + n];
  } else {                  // src [512,128]; out [n*512+k] = src[k*128+n]
    int n = off >> 9, k = off & 511;
    v = s[k * 128 + n];
  }
  out[idx] = __float2bfloat16(v);
}

// ---------------- fp32 -> bf16 convert (n_feat)
__global__ __launch_bounds__(256) void convert_bf16(const float* __restrict__ in,
                                                    bf16_t* __restrict__ out, int n) {
  int i = (blockIdx.x * 256 + threadIdx.x) * 4;
  if (i < n) {
    float4 v = *(const float4*)(in + i);
    out[i + 0] = __float2bfloat16(v.x);
    out[i + 1] = __float2bfloat16(v.y);
    out[i + 2] = __float2bfloat16(v.z);
    out[i + 3] = __float2bfloat16(v.w);
  }
}

// ---------------- MFMA GEMM: C[M,N] = A[M,K] @ B[K,N], A bf16 row-major,
// Bt bf16 [N,K] row-major. EPI: 0 = plain, 1 = +bias, relu. C bf16.
template <int EPI>
__global__ __launch_bounds__(256) void mfma_gemm(
    const bf16_t* __restrict__ A, const bf16_t* __restrict__ Bt,
    const float* __restrict__ bias, bf16_t* __restrict__ C,
    int M, int N, int K) {
  __shared__ bf16_t As[128 * 40];  // padded stride 40 (80 B) -> 2-way max
  __shared__ bf16_t Bs[128 * 40];
  int tid = threadIdx.x;
  int lane = tid & 63, wave = tid >> 6;
  int q = lane >> 4, r16 = lane & 15;
  int wm = (wave >> 1) * 64, wn = (wave & 1) * 64;
  int rowBase = blockIdx.y * 128, colBase = blockIdx.x * 128;

  f32x4 acc[4][4] = {};

  for (int k0 = 0; k0 < K; k0 += 32) {
#pragma unroll
    for (int t = 0; t < 2; t++) {
      int s = tid + t * 256;          // 512 slots of 16 B
      int row = s >> 2, kq = (s & 3) * 8;
      int gr = rowBase + row;
      bf16x8 va = {};
      if (gr < M) va = *(const bf16x8*)(A + (size_t)gr * K + k0 + kq);
      *(bf16x8*)(As + row * 40 + kq) = va;
      bf16x8 vb = *(const bf16x8*)(Bt + (size_t)(colBase + row) * K + k0 + kq);
      *(bf16x8*)(Bs + row * 40 + kq) = vb;
    }
    __syncthreads();
    bf16x8 af[4], bfr[4];
#pragma unroll
    for (int i = 0; i < 4; i++)
      af[i] = *(const bf16x8*)(As + (wm + i * 16 + r16) * 40 + q * 8);
#pragma unroll
    for (int j = 0; j < 4; j++)
      bfr[j] = *(const bf16x8*)(Bs + (wn + j * 16 + r16) * 40 + q * 8);
#pragma unroll
    for (int i = 0; i < 4; i++)
#pragma unroll
      for (int j = 0; j < 4; j++)
        acc[i][j] = __builtin_amdgcn_mfma_f32_16x16x32_bf16(af[i], bfr[j], acc[i][j], 0, 0, 0);
    __syncthreads();
  }

#pragma unroll
  for (int j = 0; j < 4; j++) {
    int col = colBase + wn + j * 16 + r16;
    float bb = (EPI == 1) ? bias[col] : 0.f;
#pragma unroll
    for (int i = 0; i < 4; i++) {
#pragma unroll
      for (int r = 0; r < 4; r++) {
        int row = rowBase + wm + i * 16 + q * 4 + r;
        if (row < M) {
          float v = acc[i][j][r];
          if (EPI == 1) v = fmaxf(v + bb, 0.f);
          C[(size_t)row * N + col] = __float2bfloat16(v);
        }
      }
    }
  }
}

// ---------------- el/er: per (node, head) dot of bf16 feat with fp32 attn vecs
__global__ __launch_bounds__(256) void el_er_kernel(
    const bf16_t* __restrict__ feat, const float* __restrict__ al,
    const float* __restrict__ ar, float* __restrict__ el,
    float* __restrict__ er, int N) {
  int n = blockIdx.x;
  int h = threadIdx.x >> 6;
  int l = threadIdx.x & 63;
  unsigned int fp = *(const unsigned int*)(feat + (size_t)n * 512 + h * 128 + l * 2);
  float f0 = bf2f((unsigned short)(fp & 0xffff));
  float f1 = bf2f((unsigned short)(fp >> 16));
  const float2 av = *(const float2*)(al + h * 128 + l * 2);
  const float2 bv = *(const float2*)(ar + h * 128 + l * 2);
  float sl = f0 * av.x + f1 * av.y;
  float sr = f0 * bv.x + f1 * bv.y;
  for (int off = 32; off; off >>= 1) {
    sl += __shfl_down(sl, off);
    sr += __shfl_down(sr, off);
  }
  if (l == 0) {
    el[n * 4 + h] = sl;
    er[n * 4 + h] = sr;
  }
}

// ---------------- CSR build
__global__ __launch_bounds__(256) void count_kernel(const int* __restrict__ dst,
                                                    int* __restrict__ counts, int E) {
  int i = blockIdx.x * blockDim.x + threadIdx.x;
  if (i < E) atomicAdd(&counts[dst[i]], 1);
}

__global__ __launch_bounds__(1024) void scan_kernel(const int* __restrict__ counts,
                                                    int* __restrict__ row_ptr,
                                                    int* __restrict__ cursor, int N) {
  __shared__ int sums[1024];
  int t = threadIdx.x;
  int chunk = (N + 1023) / 1024;
  int begin = t * chunk;
  int end = begin + chunk;
  if (end > N) end = N;
  int s = 0;
  for (int i = begin; i < end; i++) s += counts[i];
  sums[t] = s;
  __syncthreads();
  for (int off = 1; off < 1024; off <<= 1) {
    int v = (t >= off) ? sums[t - off] : 0;
    __syncthreads();
    sums[t] += v;
    __syncthreads();
  }
  int run = (t == 0) ? 0 : sums[t - 1];
  for (int i = begin; i < end; i++) {
    row_ptr[i] = run;
    cursor[i] = run;
    run += counts[i];
  }
  if (t == 1023) row_ptr[N] = sums[1023];
}

__global__ __launch_bounds__(256) void scatter_kernel(
    const int* __restrict__ src, const int* __restrict__ dst,
    int* __restrict__ cursor, int* __restrict__ edge_src, int E) {
  int i = blockIdx.x * blockDim.x + threadIdx.x;
  if (i < E) {
    int d = dst[i];
    int pos = atomicAdd(&cursor[d], 1);
    edge_src[pos] = src[i];
  }
}

// ---------------- GAT aggregation: block = node, wave = head.
__global__ __launch_bounds__(256) void gat_agg_kernel(
    const bf16_t* __restrict__ feat, const bf16_t* __restrict__ res,
    const float* __restrict__ el, const float* __restrict__ er,
    const float* __restrict__ bias, const int* __restrict__ row_ptr,
    const int* __restrict__ edge_src, bf16_t* __restrict__ out, int N) {
  int n = blockIdx.x;
  int h = threadIdx.x >> 6;
  int l = threadIdx.x & 63;
  int start = row_ptr[n];
  int deg = row_ptr[n + 1] - start;
  float er_nh = er[n * 4 + h];

  // pass 1: max over incoming-edge scores
  float m = -3.402823466e38f;
  for (int i = l; i < deg; i += 64) {
    int s = edge_src[start + i];
    float e = el[s * 4 + h] + er_nh;
    e = (e > 0.f) ? e : 0.2f * e;
    m = fmaxf(m, e);
  }
  for (int off = 32; off; off >>= 1) m = fmaxf(m, __shfl_xor(m, off));

  // pass 2: sum + weighted accumulate (all lanes walk all edges; lane = 2 dims)
  int d0 = l * 2;
  float acc0 = 0.f, acc1 = 0.f, ssum = 0.f;
  for (int i = 0; i < deg; i++) {
    int s = edge_src[start + i];
    float e = el[s * 4 + h] + er_nh;
    e = (e > 0.f) ? e : 0.2f * e;
    float w = __expf(e - m);
    ssum += w;
    unsigned int fp = *(const unsigned int*)(feat + (size_t)s * 512 + h * 128 + d0);
    acc0 += w * bf2f((unsigned short)(fp & 0xffff));
    acc1 += w * bf2f((unsigned short)(fp >> 16));
  }
  float inv = (deg > 0) ? 1.f / ssum : 0.f;
  size_t oidx = (size_t)n * 512 + h * 128 + d0;
  unsigned int rp = *(const unsigned int*)(res + oidx);
  float2 bv = *(const float2*)(bias + h * 128 + d0);
  float o0 = fmaxf(acc0 * inv + bf2f((unsigned short)(rp & 0xffff)) + bv.x, 0.f);
  float o1 = fmaxf(acc1 * inv + bf2f((unsigned short)(rp >> 16)) + bv.y, 0.f);
  unsigned int op = ((unsigned int)__bfloat16_as_ushort(__float2bfloat16(o1)) << 16) |
                    (unsigned int)__bfloat16_as_ushort(__float2bfloat16(o0));
  *(unsigned int*)(out + oidx) = op;
}

// ---------------- final: head-mean -> relu -> max over nodes
__global__ __launch_bounds__(128) void pool_kernel(const bf16_t* __restrict__ g,
                                                   float* __restrict__ out, int N) {
  int d = threadIdx.x;  // 0..127
  float mx = 0.f;
  for (int n = blockIdx.x; n < N; n += gridDim.x) {
    const bf16_t* p = g + (size_t)n * 512 + d;
    float v = 0.25f * (__bfloat162float(p[0]) + __bfloat162float(p[128]) +
                       __bfloat162float(p[256]) + __bfloat162float(p[384]));
    mx = fmaxf(mx, v);
  }
  atomicMax((int*)out + d, __float_as_int(mx));  // values are >= 0
}

// ---------------------------------------------------------------------------
extern "C" void kernel_launch(void* const* d_in, const int* in_sizes, int n_in,
                              void* d_out, int out_size, void* d_ws, size_t ws_size,
                              hipStream_t stream) {
  const float* n_feat = (const float*)d_in[0];
  const int* src = (const int*)d_in[1];
  const int* dst = (const int*)d_in[2];
  const float* W0 = (const float*)d_in[3];
  const float* al0 = (const float*)d_in[4];
  const float* ar0 = (const float*)d_in[5];
  const float* b0 = (const float*)d_in[6];
  const float* rW0 = (const float*)d_in[7];
  const float* DW0 = (const float*)d_in[8];
  const float* Db0 = (const float*)d_in[9];
  const float* W1 = (const float*)d_in[10];
  const float* al1 = (const float*)d_in[11];
  const float* ar1 = (const float*)d_in[12];
  const float* b1 = (const float*)d_in[13];
  const float* rW1 = (const float*)d_in[14];
  const float* DW1 = (const float*)d_in[15];
  const float* Db1 = (const float*)d_in[16];
  const float* W2 = (const float*)d_in[17];
  const float* al2 = (const float*)d_in[18];
  const float* ar2 = (const float*)d_in[19];
  const float* b2 = (const float*)d_in[20];
  const float* rW2 = (const float*)d_in[21];

  const int N = in_sizes[0] / 128;
  const int E = in_sizes[1];

  // ---- workspace carve-up (bf16 first, 16B-aligned throughout)
  bf16_t* xbf = (bf16_t*)d_ws;                       // [N,128]
  bf16_t* featA = xbf + (size_t)N * 128;             // [N,512]
  bf16_t* resB = featA + (size_t)N * 512;            // [N,512]
  bf16_t* outC = resB + (size_t)N * 512;             // [N,512]
  bf16_t* denseD = outC + (size_t)N * 512;           // [N,128]
  bf16_t* wts = denseD + (size_t)N * 128;            // 8 x 65536
  float* el = (float*)(wts + 8 * 65536);             // [N,4]
  float* er = el + (size_t)N * 4;                    // [N,4]
  int* counts = (int*)(er + (size_t)N * 4);          // [N]
  int* row_ptr = counts + N;                         // [N+1]
  int* cursor = row_ptr + (N + 1);                   // [N]
  int* edge_src = cursor + N;                        // [E]

  bf16_t* Wt0 = wts + 0 * 65536;
  bf16_t* rWt0 = wts + 1 * 65536;
  bf16_t* Wt1 = wts + 2 * 65536;
  bf16_t* rWt1 = wts + 3 * 65536;
  bf16_t* Wt2 = wts + 4 * 65536;
  bf16_t* rWt2 = wts + 5 * 65536;
  bf16_t* DWt0 = wts + 6 * 65536;
  bf16_t* DWt1 = wts + 7 * 65536;

  // ---- one-time prep
  prep_weights<<<2048, 256, 0, stream>>>(W0, rW0, W1, rW1, W2, rW2, DW0, DW1, wts);
  convert_bf16<<<(N * 128 / 4 + 255) / 256, 256, 0, stream>>>(n_feat, xbf, N * 128);

  hipMemsetAsync(counts, 0, (size_t)N * sizeof(int), stream);
  count_kernel<<<(E + 255) / 256, 256, 0, stream>>>(dst, counts, E);
  scan_kernel<<<1, 1024, 0, stream>>>(counts, row_ptr, cursor, N);
  scatter_kernel<<<(E + 255) / 256, 256, 0, stream>>>(src, dst, cursor, edge_src, E);

  dim3 g512(4, (N + 127) / 128);   // N-dim 512
  dim3 g128(1, (N + 127) / 128);   // N-dim 128

  // ---- layer 0 (K=128 -> 512)
  mfma_gemm<0><<<g512, 256, 0, stream>>>(xbf, Wt0, nullptr, featA, N, 512, 128);
  mfma_gemm<0><<<g512, 256, 0, stream>>>(xbf, rWt0, nullptr, resB, N, 512, 128);
  el_er_kernel<<<N, 256, 0, stream>>>(featA, al0, ar0, el, er, N);
  gat_agg_kernel<<<N, 256, 0, stream>>>(featA, resB, el, er, b0, row_ptr, edge_src, outC, N);
  mfma_gemm<1><<<g128, 256, 0, stream>>>(outC, DWt0, Db0, denseD, N, 128, 512);

  // ---- layer 1
  mfma_gemm<0><<<g512, 256, 0, stream>>>(denseD, Wt1, nullptr, featA, N, 512, 128);
  mfma_gemm<0><<<g512, 256, 0, stream>>>(denseD, rWt1, nullptr, resB, N, 512, 128);
  el_er_kernel<<<N, 256, 0, stream>>>(featA, al1, ar1, el, er, N);
  gat_agg_kernel<<<N, 256, 0, stream>>>(featA, resB, el, er, b1, row_ptr, edge_src, outC, N);
  mfma_gemm<1><<<g128, 256, 0, stream>>>(outC, DWt1, Db1, denseD, N, 128, 512);

  // ---- layer 2 + pooling
  mfma_gemm<0><<<g512, 256, 0, stream>>>(denseD, Wt2, nullptr, featA, N, 512, 128);
  mfma_gemm<0><<<g512, 256, 0, stream>>>(denseD, rWt2, nullptr, resB, N, 512, 128);
  el_er_kernel<<<N, 256, 0, stream>>>(featA, al2, ar2, el, er, N);
  gat_agg_kernel<<<N, 256, 0, stream>>>(featA, resB, el, er, b2, row_ptr, edge_src, outC, N);

  hipMemsetAsync(d_out, 0, 128 * sizeof(float), stream);
  pool_kernel<<<256, 128, 0, stream>>>(outC, (float*)d_out, N);
}

// Round 3
// 514.336 us; speedup vs baseline: 1.8137x; 1.1931x over previous
//
#include <hip/hip_runtime.h>
#include <hip/hip_bf16.h>

// ---------------------------------------------------------------------------
// PatchGAT on MI355X. Round 3: MLP-restructured aggregation (4 edge groups x
// 16 lanes x uint4 gathers), fused W||rW GEMM -> [N,1024] feat||res buffer,
// 64x64-tile dense GEMM for occupancy.
// N=20000, E=320000, F_IN=HID=OUT=128, H=4, H*D=512.
// ---------------------------------------------------------------------------

typedef __attribute__((ext_vector_type(8))) short bf16x8;
typedef __attribute__((ext_vector_type(4))) float f32x4;
typedef __hip_bfloat16 bf16_t;

// ---------------- weight prep:
// fused L in {0,1,2}: [1024,128] bf16, rows 0-511 = W_L^T, 512-1023 = rW_L^T
// dense d in {0,1}:   [128,512]  bf16, row n = col n of DW_d
__global__ __launch_bounds__(256) void prep_weights(
    const float* __restrict__ W0, const float* __restrict__ rW0,
    const float* __restrict__ W1, const float* __restrict__ rW1,
    const float* __restrict__ W2, const float* __restrict__ rW2,
    const float* __restrict__ DW0, const float* __restrict__ DW1,
    bf16_t* __restrict__ out) {
  int idx = blockIdx.x * 256 + threadIdx.x;  // 0 .. 524287
  float v;
  if (idx < 393216) {
    int mat = idx / 131072;  // 0..2
    int off = idx & 131071;
    int n = off >> 7, k = off & 127;
    const float* W = (mat == 0) ? W0 : (mat == 1) ? W1 : W2;
    const float* rW = (mat == 0) ? rW0 : (mat == 1) ? rW1 : rW2;
    v = (n < 512) ? W[k * 512 + n] : rW[k * 512 + (n - 512)];
  } else {
    int rem = idx - 393216;
    int mat = rem >> 16;  // 0..1
    int off = rem & 65535;
    int n = off >> 9, k = off & 511;
    const float* DW = mat ? DW1 : DW0;
    v = DW[k * 128 + n];
  }
  out[idx] = __float2bfloat16(v);
}

// ---------------- fp32 -> bf16 convert (n_feat)
__global__ __launch_bounds__(256) void convert_bf16(const float* __restrict__ in,
                                                    bf16_t* __restrict__ out, int n) {
  int i = (blockIdx.x * 256 + threadIdx.x) * 4;
  if (i < n) {
    float4 v = *(const float4*)(in + i);
    out[i + 0] = __float2bfloat16(v.x);
    out[i + 1] = __float2bfloat16(v.y);
    out[i + 2] = __float2bfloat16(v.z);
    out[i + 3] = __float2bfloat16(v.w);
  }
}

// ---------------- 128x128-tile MFMA GEMM: C[M,ldc] = A[M,K] @ Bt[ldc,K]^T
// A row-major stride K; Bt row-major [Ncols,K]; C bf16 stride ldc.
__global__ __launch_bounds__(256) void mfma_gemm128(
    const bf16_t* __restrict__ A, const bf16_t* __restrict__ Bt,
    bf16_t* __restrict__ C, int M, int ldc, int K) {
  __shared__ bf16_t As[128 * 40];  // stride 40 (80 B): 2-way max conflicts
  __shared__ bf16_t Bs[128 * 40];
  int tid = threadIdx.x;
  int lane = tid & 63, wave = tid >> 6;
  int q = lane >> 4, r16 = lane & 15;
  int wm = (wave >> 1) * 64, wn = (wave & 1) * 64;
  int rowBase = blockIdx.y * 128, colBase = blockIdx.x * 128;

  f32x4 acc[4][4] = {};

  for (int k0 = 0; k0 < K; k0 += 32) {
#pragma unroll
    for (int t = 0; t < 2; t++) {
      int s = tid + t * 256;  // 512 slots of 16 B
      int row = s >> 2, kq = (s & 3) * 8;
      int gr = rowBase + row;
      bf16x8 va = {};
      if (gr < M) va = *(const bf16x8*)(A + (size_t)gr * K + k0 + kq);
      *(bf16x8*)(As + row * 40 + kq) = va;
      bf16x8 vb = *(const bf16x8*)(Bt + (size_t)(colBase + row) * K + k0 + kq);
      *(bf16x8*)(Bs + row * 40 + kq) = vb;
    }
    __syncthreads();
    bf16x8 af[4], bfr[4];
#pragma unroll
    for (int i = 0; i < 4; i++)
      af[i] = *(const bf16x8*)(As + (wm + i * 16 + r16) * 40 + q * 8);
#pragma unroll
    for (int j = 0; j < 4; j++)
      bfr[j] = *(const bf16x8*)(Bs + (wn + j * 16 + r16) * 40 + q * 8);
#pragma unroll
    for (int i = 0; i < 4; i++)
#pragma unroll
      for (int j = 0; j < 4; j++)
        acc[i][j] = __builtin_amdgcn_mfma_f32_16x16x32_bf16(af[i], bfr[j], acc[i][j], 0, 0, 0);
    __syncthreads();
  }

#pragma unroll
  for (int j = 0; j < 4; j++) {
    int col = colBase + wn + j * 16 + r16;
#pragma unroll
    for (int i = 0; i < 4; i++) {
#pragma unroll
      for (int r = 0; r < 4; r++) {
        int row = rowBase + wm + i * 16 + q * 4 + r;
        if (row < M) C[(size_t)row * ldc + col] = __float2bfloat16(acc[i][j][r]);
      }
    }
  }
}

// ---------------- 64x64-tile MFMA GEMM with bias+relu (dense layers)
__global__ __launch_bounds__(256) void mfma_gemm64(
    const bf16_t* __restrict__ A, const bf16_t* __restrict__ Bt,
    const float* __restrict__ bias, bf16_t* __restrict__ C,
    int M, int ldc, int K) {
  __shared__ bf16_t As[64 * 40];
  __shared__ bf16_t Bs[64 * 40];
  int tid = threadIdx.x;
  int lane = tid & 63, wave = tid >> 6;
  int q = lane >> 4, r16 = lane & 15;
  int wm = (wave >> 1) * 32, wn = (wave & 1) * 32;
  int rowBase = blockIdx.y * 64, colBase = blockIdx.x * 64;
  int row = tid >> 2, kq = (tid & 3) * 8;  // 256 slots exactly

  f32x4 acc[2][2] = {};

  for (int k0 = 0; k0 < K; k0 += 32) {
    int gr = rowBase + row;
    bf16x8 va = {};
    if (gr < M) va = *(const bf16x8*)(A + (size_t)gr * K + k0 + kq);
    *(bf16x8*)(As + row * 40 + kq) = va;
    bf16x8 vb = *(const bf16x8*)(Bt + (size_t)(colBase + row) * K + k0 + kq);
    *(bf16x8*)(Bs + row * 40 + kq) = vb;
    __syncthreads();
    bf16x8 af[2], bfr[2];
#pragma unroll
    for (int i = 0; i < 2; i++)
      af[i] = *(const bf16x8*)(As + (wm + i * 16 + r16) * 40 + q * 8);
#pragma unroll
    for (int j = 0; j < 2; j++)
      bfr[j] = *(const bf16x8*)(Bs + (wn + j * 16 + r16) * 40 + q * 8);
#pragma unroll
    for (int i = 0; i < 2; i++)
#pragma unroll
      for (int j = 0; j < 2; j++)
        acc[i][j] = __builtin_amdgcn_mfma_f32_16x16x32_bf16(af[i], bfr[j], acc[i][j], 0, 0, 0);
    __syncthreads();
  }

#pragma unroll
  for (int j = 0; j < 2; j++) {
    int col = colBase + wn + j * 16 + r16;
    float bb = bias[col];
#pragma unroll
    for (int i = 0; i < 2; i++) {
#pragma unroll
      for (int r = 0; r < 4; r++) {
        int rw = rowBase + wm + i * 16 + q * 4 + r;
        if (rw < M) C[(size_t)rw * ldc + col] = __float2bfloat16(fmaxf(acc[i][j][r] + bb, 0.f));
      }
    }
  }
}

// ---------------- el/er over fused [N,1024] buffer (feat = cols 0-511)
__global__ __launch_bounds__(256) void el_er_kernel(
    const bf16_t* __restrict__ fused, const float* __restrict__ al,
    const float* __restrict__ ar, float* __restrict__ el,
    float* __restrict__ er, int N) {
  int n = blockIdx.x;
  int h = threadIdx.x >> 6;
  int l = threadIdx.x & 63;
  unsigned int fp = *(const unsigned int*)(fused + (size_t)n * 1024 + h * 128 + l * 2);
  float f0 = __uint_as_float(fp << 16);
  float f1 = __uint_as_float(fp & 0xffff0000u);
  const float2 av = *(const float2*)(al + h * 128 + l * 2);
  const float2 bv = *(const float2*)(ar + h * 128 + l * 2);
  float sl = f0 * av.x + f1 * av.y;
  float sr = f0 * bv.x + f1 * bv.y;
  for (int off = 32; off; off >>= 1) {
    sl += __shfl_down(sl, off);
    sr += __shfl_down(sr, off);
  }
  if (l == 0) {
    el[n * 4 + h] = sl;
    er[n * 4 + h] = sr;
  }
}

// ---------------- CSR build
__global__ __launch_bounds__(256) void count_kernel(const int* __restrict__ dst,
                                                    int* __restrict__ counts, int E) {
  int i = blockIdx.x * blockDim.x + threadIdx.x;
  if (i < E) atomicAdd(&counts[dst[i]], 1);
}

__global__ __launch_bounds__(1024) void scan_kernel(const int* __restrict__ counts,
                                                    int* __restrict__ row_ptr,
                                                    int* __restrict__ cursor, int N) {
  __shared__ int sums[1024];
  int t = threadIdx.x;
  int chunk = (N + 1023) / 1024;
  int begin = t * chunk;
  int end = begin + chunk;
  if (end > N) end = N;
  int s = 0;
  for (int i = begin; i < end; i++) s += counts[i];
  sums[t] = s;
  __syncthreads();
  for (int off = 1; off < 1024; off <<= 1) {
    int v = (t >= off) ? sums[t - off] : 0;
    __syncthreads();
    sums[t] += v;
    __syncthreads();
  }
  int run = (t == 0) ? 0 : sums[t - 1];
  for (int i = begin; i < end; i++) {
    row_ptr[i] = run;
    cursor[i] = run;
    run += counts[i];
  }
  if (t == 1023) row_ptr[N] = sums[1023];
}

__global__ __launch_bounds__(256) void scatter_kernel(
    const int* __restrict__ src, const int* __restrict__ dst,
    int* __restrict__ cursor, int* __restrict__ edge_src, int E) {
  int i = blockIdx.x * blockDim.x + threadIdx.x;
  if (i < E) {
    int d = dst[i];
    int pos = atomicAdd(&cursor[d], 1);
    edge_src[pos] = src[i];
  }
}

// ---------------- GAT aggregation: block = node, wave = head.
// Pass 2: 4 edge groups (16 lanes each); lane covers 8 dims via one uint4;
// 4 independent gather chains per wave -> 4x MLP vs serial walk.
__global__ __launch_bounds__(256) void gat_agg_kernel(
    const bf16_t* __restrict__ fused,  // [N,1024]: cols 0-511 feat, 512-1023 res
    const float* __restrict__ el, const float* __restrict__ er,
    const float* __restrict__ bias, const int* __restrict__ row_ptr,
    const int* __restrict__ edge_src, bf16_t* __restrict__ out, int N) {
  int n = blockIdx.x;
  int h = threadIdx.x >> 6;
  int l = threadIdx.x & 63;
  int g = l >> 4, t = l & 15;
  int start = row_ptr[n];
  int deg = row_ptr[n + 1] - start;
  float er_nh = er[n * 4 + h];

  // pass 1: max over incoming-edge scores (strided over 64 lanes)
  float m = -3.402823466e38f;
  for (int i = l; i < deg; i += 64) {
    int s = edge_src[start + i];
    float e = el[s * 4 + h] + er_nh;
    e = (e > 0.f) ? e : 0.2f * e;
    m = fmaxf(m, e);
  }
#pragma unroll
  for (int off = 32; off; off >>= 1) m = fmaxf(m, __shfl_xor(m, off));

  // pass 2: group g walks edges g, g+4, ...
  float acc[8] = {};
  float ssum = 0.f;
  for (int i = g; i < deg; i += 4) {
    int s = edge_src[start + i];
    float e = el[s * 4 + h] + er_nh;
    e = (e > 0.f) ? e : 0.2f * e;
    float w = __expf(e - m);
    ssum += w;
    uint4 fp = *(const uint4*)(fused + (size_t)s * 1024 + h * 128 + t * 8);
    unsigned int u0 = fp.x, u1 = fp.y, u2 = fp.z, u3 = fp.w;
    acc[0] += w * __uint_as_float(u0 << 16);
    acc[1] += w * __uint_as_float(u0 & 0xffff0000u);
    acc[2] += w * __uint_as_float(u1 << 16);
    acc[3] += w * __uint_as_float(u1 & 0xffff0000u);
    acc[4] += w * __uint_as_float(u2 << 16);
    acc[5] += w * __uint_as_float(u2 & 0xffff0000u);
    acc[6] += w * __uint_as_float(u3 << 16);
    acc[7] += w * __uint_as_float(u3 & 0xffff0000u);
  }
  // reduce the 4 groups
#pragma unroll
  for (int off = 16; off <= 32; off <<= 1) {
    ssum += __shfl_xor(ssum, off);
#pragma unroll
    for (int d = 0; d < 8; d++) acc[d] += __shfl_xor(acc[d], off);
  }

  if (g == 0) {
    float inv = (deg > 0) ? 1.f / ssum : 0.f;
    uint4 rp = *(const uint4*)(fused + (size_t)n * 1024 + 512 + h * 128 + t * 8);
    const float* bp = bias + h * 128 + t * 8;
    unsigned int ru[4] = {rp.x, rp.y, rp.z, rp.w};
    unsigned int ow[4];
#pragma unroll
    for (int j = 0; j < 4; j++) {
      float o0 = fmaxf(acc[2 * j] * inv + __uint_as_float(ru[j] << 16) + bp[2 * j], 0.f);
      float o1 = fmaxf(acc[2 * j + 1] * inv + __uint_as_float(ru[j] & 0xffff0000u) + bp[2 * j + 1], 0.f);
      ow[j] = (((unsigned int)__bfloat16_as_ushort(__float2bfloat16(o1))) << 16) |
              (unsigned int)__bfloat16_as_ushort(__float2bfloat16(o0));
    }
    *(uint4*)(out + (size_t)n * 512 + h * 128 + t * 8) = make_uint4(ow[0], ow[1], ow[2], ow[3]);
  }
}

// ---------------- final: head-mean -> relu -> max over nodes
__global__ __launch_bounds__(128) void pool_kernel(const bf16_t* __restrict__ g,
                                                   float* __restrict__ out, int N) {
  int d = threadIdx.x;  // 0..127
  float mx = 0.f;
  for (int n = blockIdx.x; n < N; n += gridDim.x) {
    const bf16_t* p = g + (size_t)n * 512 + d;
    float v = 0.25f * (__bfloat162float(p[0]) + __bfloat162float(p[128]) +
                       __bfloat162float(p[256]) + __bfloat162float(p[384]));
    mx = fmaxf(mx, v);
  }
  atomicMax((int*)out + d, __float_as_int(mx));  // values are >= 0
}

// ---------------------------------------------------------------------------
extern "C" void kernel_launch(void* const* d_in, const int* in_sizes, int n_in,
                              void* d_out, int out_size, void* d_ws, size_t ws_size,
                              hipStream_t stream) {
  const float* n_feat = (const float*)d_in[0];
  const int* src = (const int*)d_in[1];
  const int* dst = (const int*)d_in[2];
  const float* W0 = (const float*)d_in[3];
  const float* al0 = (const float*)d_in[4];
  const float* ar0 = (const float*)d_in[5];
  const float* b0 = (const float*)d_in[6];
  const float* rW0 = (const float*)d_in[7];
  const float* DW0 = (const float*)d_in[8];
  const float* Db0 = (const float*)d_in[9];
  const float* W1 = (const float*)d_in[10];
  const float* al1 = (const float*)d_in[11];
  const float* ar1 = (const float*)d_in[12];
  const float* b1 = (const float*)d_in[13];
  const float* rW1 = (const float*)d_in[14];
  const float* DW1 = (const float*)d_in[15];
  const float* Db1 = (const float*)d_in[16];
  const float* W2 = (const float*)d_in[17];
  const float* al2 = (const float*)d_in[18];
  const float* ar2 = (const float*)d_in[19];
  const float* b2 = (const float*)d_in[20];
  const float* rW2 = (const float*)d_in[21];

  const int N = in_sizes[0] / 128;
  const int E = in_sizes[1];

  // ---- workspace carve-up (16B-aligned throughout)
  bf16_t* xbf = (bf16_t*)d_ws;                        // [N,128]
  bf16_t* fusedFR = xbf + (size_t)N * 128;            // [N,1024] feat||res
  bf16_t* outC = fusedFR + (size_t)N * 1024;          // [N,512]
  bf16_t* denseD = outC + (size_t)N * 512;            // [N,128]
  bf16_t* wts = denseD + (size_t)N * 128;             // 524288
  float* el = (float*)(wts + 524288);                 // [N,4]
  float* er = el + (size_t)N * 4;                     // [N,4]
  int* counts = (int*)(er + (size_t)N * 4);           // [N]
  int* row_ptr = counts + N;                          // [N+1]
  int* cursor = row_ptr + (N + 1);                    // [N]
  int* edge_src = cursor + N;                         // [E]

  bf16_t* FW0 = wts;                // [1024,128]
  bf16_t* FW1 = wts + 131072;
  bf16_t* FW2 = wts + 262144;
  bf16_t* DWt0 = wts + 393216;      // [128,512]
  bf16_t* DWt1 = wts + 458752;

  // ---- one-time prep
  prep_weights<<<2048, 256, 0, stream>>>(W0, rW0, W1, rW1, W2, rW2, DW0, DW1, wts);
  convert_bf16<<<(N * 128 / 4 + 255) / 256, 256, 0, stream>>>(n_feat, xbf, N * 128);

  hipMemsetAsync(counts, 0, (size_t)N * sizeof(int), stream);
  count_kernel<<<(E + 255) / 256, 256, 0, stream>>>(dst, counts, E);
  scan_kernel<<<1, 1024, 0, stream>>>(counts, row_ptr, cursor, N);
  scatter_kernel<<<(E + 255) / 256, 256, 0, stream>>>(src, dst, cursor, edge_src, E);

  dim3 gF(8, (N + 127) / 128);    // fused: 1024 cols
  dim3 gD(2, (N + 63) / 64);      // dense: 128 cols, 64-tile

  // ---- layer 0
  mfma_gemm128<<<gF, 256, 0, stream>>>(xbf, FW0, fusedFR, N, 1024, 128);
  el_er_kernel<<<N, 256, 0, stream>>>(fusedFR, al0, ar0, el, er, N);
  gat_agg_kernel<<<N, 256, 0, stream>>>(fusedFR, el, er, b0, row_ptr, edge_src, outC, N);
  mfma_gemm64<<<gD, 256, 0, stream>>>(outC, DWt0, Db0, denseD, N, 128, 512);

  // ---- layer 1
  mfma_gemm128<<<gF, 256, 0, stream>>>(denseD, FW1, fusedFR, N, 1024, 128);
  el_er_kernel<<<N, 256, 0, stream>>>(fusedFR, al1, ar1, el, er, N);
  gat_agg_kernel<<<N, 256, 0, stream>>>(fusedFR, el, er, b1, row_ptr, edge_src, outC, N);
  mfma_gemm64<<<gD, 256, 0, stream>>>(outC, DWt1, Db1, denseD, N, 128, 512);

  // ---- layer 2 + pooling
  mfma_gemm128<<<gF, 256, 0, stream>>>(denseD, FW2, fusedFR, N, 1024, 128);
  el_er_kernel<<<N, 256, 0, stream>>>(fusedFR, al2, ar2, el, er, N);
  gat_agg_kernel<<<N, 256, 0, stream>>>(fusedFR, el, er, b2, row_ptr, edge_src, outC, N);

  hipMemsetAsync(d_out, 0, 128 * sizeof(float), stream);
  pool_kernel<<<256, 128, 0, stream>>>(outC, (float*)d_out, N);
}